// Round 13
// baseline (95.618 us; speedup 1.0000x reference)
//
#include <hip/hip_runtime.h>
#include <hip/hip_bf16.h>

// Problem: B=4096, IN=1024, H=1024.
// pre = x@U^T + h@W^T + Ub -> gates -> h_t, c_t   (fused after convert)
// GEMM: M=4096 (batch), N=4096 (4H permuted), K=2048 (IN+H concat)
//
// Round-13: r12's 2-blocks/CU structure with a FRAME-CORRECT swizzle.
// r12's 4-slot/64B-row swizzle caused 8.4M bank conflicts (rows fold into
// the 128-B bank frame in parity pairs; per-parity XOR packed 8 lanes/cell).
// Fix: swizzle the full 128-B frame (2 rows of 32 bf16 = 8 x 16B cells):
//   logical cell l = (row&1)*4 + kq;  phys cell = l ^ (line&7), line=row>>1.
// Reader (rows base+frow, base mult of 16): cell is per-lane constant:
//   cell = ((frow&1)<<2 | kq) ^ ((frow>>1)&7)
// -> each 16-lane group covers all 8 cells exactly 2x = the r8-r11
// measured-zero-conflict pattern.
// Stager thread tid: l = (tid&7)^((tid>>3)&7); srcrow = ((tid>>3)<<1)|(l>>2);
//   scol = (l&3)*8 elems. B chunk2 = same + 128 rows (frame fn invariant).
// Ring/vmcnt/barrier ledger identical to r12 (proven correct there).

#define BATCH 4096
#define HID   1024
#define KDIM  2048

#define BM 128
#define BN 256
#define BK 32
#define NT (KDIM / BK)        // 64 K-tiles
#define SLOT_BYTES 24576u     // A 8 KB + B 16 KB

typedef __bf16 bf16x8 __attribute__((ext_vector_type(8)));
typedef float  f32x4  __attribute__((ext_vector_type(4)));

__device__ __forceinline__ void async_load16(const void* g, void* l) {
    __builtin_amdgcn_global_load_lds(
        (const __attribute__((address_space(1))) void*)g,
        (__attribute__((address_space(3))) void*)l,
        16, 0, 0);
}

__device__ __forceinline__ float sigmoidf_(float v) {
    return 1.0f / (1.0f + __expf(-v));
}
__device__ __forceinline__ float tanhf_(float v) {
    return 1.0f - 2.0f / (__expf(2.0f * v) + 1.0f);
}

// ---------------------------------------------------------------------------
// Kernel 1: f32 -> bf16 conversion + K-concat; B side gate-permuted.
// ---------------------------------------------------------------------------
__global__ __launch_bounds__(256) void convert_kernel(
    const float* __restrict__ x, const float* __restrict__ h,
    const float* __restrict__ U, const float* __restrict__ W,
    __hip_bfloat16* __restrict__ Acat, __hip_bfloat16* __restrict__ Bcat)
{
    const int CH_PER_MAT = (4096 * KDIM) / 8;
    int idx = blockIdx.x * blockDim.x + threadIdx.x;
    bool isB = idx >= CH_PER_MAT;
    int c = isB ? (idx - CH_PER_MAT) : idx;
    int row  = c >> 8;
    int col  = (c & 255) << 3;
    int srow = row;
    if (isB) {
        int g  = (row >> 4) & 3;
        int j  = ((row >> 8) << 6) + (((row >> 6) & 3) << 4) + (row & 15);
        srow = g * 1024 + j;
    }
    const float* src;
    if (col < 1024) src = (isB ? U : x) + (size_t)srow * 1024 + col;
    else            src = (isB ? W : h) + (size_t)srow * 1024 + (col - 1024);
    float4 v0 = *(const float4*)(src);
    float4 v1 = *(const float4*)(src + 4);
    __hip_bfloat16 tmp[8];
    tmp[0] = __float2bfloat16(v0.x); tmp[1] = __float2bfloat16(v0.y);
    tmp[2] = __float2bfloat16(v0.z); tmp[3] = __float2bfloat16(v0.w);
    tmp[4] = __float2bfloat16(v1.x); tmp[5] = __float2bfloat16(v1.y);
    tmp[6] = __float2bfloat16(v1.z); tmp[7] = __float2bfloat16(v1.w);
    __hip_bfloat16* dst = (isB ? Bcat : Acat) + (size_t)row * KDIM + col;
    *(bf16x8*)dst = *(const bf16x8*)tmp;
}

// ---------------------------------------------------------------------------
// Kernel 2: fused bf16 GEMM + LSTM gates, 2-blocks/CU ring schedule.
// ---------------------------------------------------------------------------
__global__ __launch_bounds__(512, 4) void gemm_lstm_kernel(
    const __hip_bfloat16* __restrict__ A,   // [4096][2048]
    const __hip_bfloat16* __restrict__ Bm,  // [4096][2048] gate-permuted
    const float* __restrict__ Ub,           // [4096]
    const float* __restrict__ c_prev,       // [4096][1024]
    float* __restrict__ out)                // h_t ++ c_t
{
    __shared__ __align__(16) unsigned char smem[3 * SLOT_BYTES];  // 72 KB

    const int tid  = threadIdx.x;
    const int lane = tid & 63;
    const int wid  = tid >> 6;
    const int wm   = wid >> 2;     // 0..1  (M half of 128)
    const int wn   = wid & 3;      // 0..3  (N quarter of 256)

    // L2 map: 512 blocks; each XCD owns an 8bm x 8bn rectangle of the
    // 32 x 16 block grid.
    int wg  = blockIdx.x;
    const int xcd = wg & 7;
    const int i_  = wg >> 3;                 // 0..63
    const int bm = ((xcd >> 1) << 3) + (i_ >> 3);   // 0..31
    const int bn = ((xcd & 1) << 3) + (i_ & 7);     // 0..15

    const __hip_bfloat16* Ab = A  + (size_t)bm * BM * KDIM;
    const __hip_bfloat16* Bb = Bm + (size_t)bn * BN * KDIM;

    // --- ds_read addressing (frame swizzle). Fragment row = base + frow,
    // base mult of 16. addr = base*64 + (frow>>1)*128 + cell*16,
    // cell = ((frow&1)<<2 | kq) ^ ((frow>>1)&7)  (per-lane constant).
    const int frow = lane & 15;
    const int kq   = lane >> 4;                         // 0..3
    const unsigned cell = (unsigned)((((frow & 1) << 2) | kq) ^ ((frow >> 1) & 7));
    const unsigned rdo  = (unsigned)((frow >> 1) * 128) + (cell << 4);

    // --- staging: linear LDS dest (chunk ch -> byte ch*16); source derived
    // from the frame involution: l = (tid&7)^((tid>>3)&7),
    // srcrow = ((tid>>3)<<1)|(l>>2), scol = (l&3)*8 elems.
    const int l_   = (tid & 7) ^ ((tid >> 3) & 7);
    const int srow_ = ((tid >> 3) << 1) | (l_ >> 2);
    const int scol_ = (l_ & 3) << 3;
    const size_t ga = (size_t)srow_ * KDIM + scol_;

    f32x4 acc[4][4] = {};

#define RD16(B) (*(const bf16x8*)(smem + (B)))
#define STAGE(TSRC, SLOT) do { \
    unsigned char* _b = smem + (SLOT) * SLOT_BYTES; \
    const size_t _k = (size_t)(TSRC) * BK; \
    async_load16(Ab + ga + _k, _b + (unsigned)tid * 16u); \
    async_load16(Bb + ga + _k, _b + 8192u + (unsigned)tid * 16u); \
    async_load16(Bb + ga + (size_t)128 * KDIM + _k, \
                 _b + 16384u + (unsigned)tid * 16u); } while (0)

    // ---- prologue: stage t0 -> slot0, t1 -> slot1; vmcnt(3) lands t0 ----
    STAGE(0, 0);
    STAGE(1, 1);
    asm volatile("s_waitcnt vmcnt(3)" ::: "memory");
    __builtin_amdgcn_s_barrier();

    int s_cur = 0, s_dst = 2;
#pragma unroll 1
    for (int t = 0; t < NT; ++t) {
        const int tsrc = (t + 2 < NT) ? (t + 2) : (NT - 1);  // clamp (dummy tail)
        STAGE(tsrc, s_dst);

        const unsigned ab = (unsigned)s_cur * SLOT_BYTES;
        const unsigned bb = ab + 8192u;
        bf16x8 af[4], bf[4];
#pragma unroll
        for (int m = 0; m < 4; ++m)
            af[m] = RD16(ab + (unsigned)((wm * 64 + m * 16) * 64) + rdo);
#pragma unroll
        for (int n = 0; n < 4; ++n)
            bf[n] = RD16(bb + (unsigned)((wn * 64 + n * 16) * 64) + rdo);

#pragma unroll
        for (int m = 0; m < 4; ++m)
#pragma unroll
            for (int n = 0; n < 4; ++n)
                acc[m][n] = __builtin_amdgcn_mfma_f32_16x16x32_bf16(
                    af[m], bf[n], acc[m][n], 0, 0, 0);

        // t+1 landed (t+2's 3 loads stay in flight); visible to all after BAR
        asm volatile("s_waitcnt vmcnt(3)" ::: "memory");
        __builtin_amdgcn_s_barrier();

        s_cur = (s_cur == 2) ? 0 : s_cur + 1;
        s_dst = (s_dst == 2) ? 0 : s_dst + 1;
    }
#undef RD16
#undef STAGE

    // ---- fused epilogue: gates lane-local thanks to B permutation ----
    const int j = bn * 64 + wn * 16 + frow;
    const float bf_ = Ub[j];
    const float bi_ = Ub[1024 + j];
    const float bo_ = Ub[2048 + j];
    const float bg_ = Ub[3072 + j];
    const int row0 = bm * BM + wm * 64 + ((lane >> 4) << 2);

    float cp[4][4];
#pragma unroll
    for (int m = 0; m < 4; ++m)
#pragma unroll
        for (int r = 0; r < 4; ++r)
            cp[m][r] = c_prev[(size_t)(row0 + m * 16 + r) * HID + j];

#pragma unroll
    for (int m = 0; m < 4; ++m) {
#pragma unroll
        for (int r = 0; r < 4; ++r) {
            const int row = row0 + m * 16 + r;
            const float f  = sigmoidf_(acc[m][0][r] + bf_);
            const float it = sigmoidf_(acc[m][1][r] + bi_);
            const float o  = sigmoidf_(acc[m][2][r] + bo_);
            const float gg = tanhf_(acc[m][3][r] + bg_);
            const float cv = f * cp[m][r] + it * gg;
            const float hv = o * tanhf_(cv);
            out[(size_t)row * HID + j] = hv;
            out[(size_t)BATCH * HID + (size_t)row * HID + j] = cv;
        }
    }
}

// ---------------------------------------------------------------------------
extern "C" void kernel_launch(void* const* d_in, const int* in_sizes, int n_in,
                              void* d_out, int out_size, void* d_ws, size_t ws_size,
                              hipStream_t stream) {
    const float* x      = (const float*)d_in[0];
    const float* h_prev = (const float*)d_in[1];
    const float* c_prev = (const float*)d_in[2];
    const float* U_w    = (const float*)d_in[3];
    const float* U_b    = (const float*)d_in[4];
    const float* W_w    = (const float*)d_in[5];
    float* out = (float*)d_out;

    char* ws = (char*)d_ws;
    __hip_bfloat16* Acat = (__hip_bfloat16*)ws;                      // 16 MB
    __hip_bfloat16* Bcat = (__hip_bfloat16*)(ws + (16u << 20));      // 16 MB

    convert_kernel<<<8192, 256, 0, stream>>>(x, h_prev, U_w, W_w, Acat, Bcat);
    // (4096/128) * (4096/256) = 32 * 16 = 512 blocks, 2 per CU
    gemm_lstm_kernel<<<512, 512, 0, stream>>>(Acat, Bcat, U_b, c_prev, out);
}

// Round 14
// 81.991 us; speedup vs baseline: 1.1662x; 1.1662x over previous
//
#include <hip/hip_runtime.h>
#include <hip/hip_bf16.h>

// Problem: B=4096, IN=1024, H=1024.
// pre = x@U^T + h@W^T + Ub -> gates -> h_t, c_t   (fused after convert)
// GEMM: M=4096 (batch), N=4096 (4H permuted), K=2048 (IN+H concat)
//
// Round-14: RESTORE round-9 configuration (best measured: 83.6 us total,
// gemm 71.0 us, 961 TF, MfmaUtil ~40%, 0 bank conflicts). Rounds 10-13
// (faithful m201 skeleton, 2-blocks/CU +-conflicts) all regressed or were
// neutral; r9's 8-phase distance-1 E/O ping-pong schedule is the optimum
// found across eight structural variants.
//
// Schedule (8 phases / 2 K-tiles per iter, BK=64, 2 LDS buffers 128 KB):
//   each phase: {ds_read quad for NEXT phase (E/O reg ping-pong) || stage
//   1 half-tile} -> setprio(1) 16 MFMA setprio(0) -> [lgkm drain at odd
//   phases; vmcnt(4) at ph3/ph7] -> s_barrier.
// Write-safety: odd-phase lgkmcnt(0) drains ensure a region's in-flight
// ds_reads complete >=1 barrier before its restage. vmcnt(4) at ph3/ph7
// retires the full next K-tile (16 stage-loads/iter/thread; 4 newest left
// in flight) before its reads; barrier makes it cross-wave visible.

#define BATCH 4096
#define HID   1024
#define KDIM  2048

#define BM 256
#define BN 256
#define BK 64
#define NITER (KDIM / (2 * BK))   // 16

typedef __bf16 bf16x8 __attribute__((ext_vector_type(8)));
typedef float  f32x4  __attribute__((ext_vector_type(4)));

__device__ __forceinline__ void async_load16(const void* g, void* l) {
    __builtin_amdgcn_global_load_lds(
        (const __attribute__((address_space(1))) void*)g,
        (__attribute__((address_space(3))) void*)l,
        16, 0, 0);
}

__device__ __forceinline__ float sigmoidf_(float v) {
    return 1.0f / (1.0f + __expf(-v));
}
__device__ __forceinline__ float tanhf_(float v) {
    return 1.0f - 2.0f / (__expf(2.0f * v) + 1.0f);
}

// ---------------------------------------------------------------------------
// Kernel 1: f32 -> bf16 conversion + K-concat; B side gate-permuted.
// ---------------------------------------------------------------------------
__global__ __launch_bounds__(256) void convert_kernel(
    const float* __restrict__ x, const float* __restrict__ h,
    const float* __restrict__ U, const float* __restrict__ W,
    __hip_bfloat16* __restrict__ Acat, __hip_bfloat16* __restrict__ Bcat)
{
    const int CH_PER_MAT = (4096 * KDIM) / 8;
    int idx = blockIdx.x * blockDim.x + threadIdx.x;
    bool isB = idx >= CH_PER_MAT;
    int c = isB ? (idx - CH_PER_MAT) : idx;
    int row  = c >> 8;
    int col  = (c & 255) << 3;
    int srow = row;
    if (isB) {
        int g  = (row >> 4) & 3;
        int j  = ((row >> 8) << 6) + (((row >> 6) & 3) << 4) + (row & 15);
        srow = g * 1024 + j;
    }
    const float* src;
    if (col < 1024) src = (isB ? U : x) + (size_t)srow * 1024 + col;
    else            src = (isB ? W : h) + (size_t)srow * 1024 + (col - 1024);
    float4 v0 = *(const float4*)(src);
    float4 v1 = *(const float4*)(src + 4);
    __hip_bfloat16 tmp[8];
    tmp[0] = __float2bfloat16(v0.x); tmp[1] = __float2bfloat16(v0.y);
    tmp[2] = __float2bfloat16(v0.z); tmp[3] = __float2bfloat16(v0.w);
    tmp[4] = __float2bfloat16(v1.x); tmp[5] = __float2bfloat16(v1.y);
    tmp[6] = __float2bfloat16(v1.z); tmp[7] = __float2bfloat16(v1.w);
    __hip_bfloat16* dst = (isB ? Bcat : Acat) + (size_t)row * KDIM + col;
    *(bf16x8*)dst = *(const bf16x8*)tmp;
}

// ---------------------------------------------------------------------------
// Kernel 2: fused bf16 GEMM + LSTM gates, 8-phase schedule (r9 config).
// ---------------------------------------------------------------------------
__global__ __launch_bounds__(512, 1) void gemm_lstm_kernel(
    const __hip_bfloat16* __restrict__ A,   // [4096][2048]
    const __hip_bfloat16* __restrict__ Bm,  // [4096][2048] gate-permuted
    const float* __restrict__ Ub,           // [4096]
    const float* __restrict__ c_prev,       // [4096][1024]
    float* __restrict__ out)                // h_t ++ c_t
{
    __shared__ __align__(16) unsigned char smem[131072];  // 2 bufs x 64 KB

    const int tid  = threadIdx.x;
    const int lane = tid & 63;
    const int wid  = tid >> 6;
    const int wm   = wid >> 2;     // 0..1
    const int wn   = wid & 3;      // 0..3

    // L2-locality map (r7): each XCD owns a 4x8 rectangle of the 16x16 grid.
    int wg  = blockIdx.x;
    const int xcd = wg & 7;
    const int i_  = wg >> 3;
    const int bm = ((xcd >> 1) << 2) + (i_ >> 3);
    const int bn = ((xcd & 1) << 3) + (i_ & 7);

    const __hip_bfloat16* Ab = A  + (size_t)bm * BM * KDIM;
    const __hip_bfloat16* Bb = Bm + (size_t)bn * BN * KDIM;

    // ds_read addressing: half-tile [128 rows][64 cols] bf16, 8 x 16B slots/row.
    // swizzle: phys_slot = logical_slot ^ ((row>>1)&7).
    const int frow = lane & 15;
    const int kq   = lane >> 4;                       // 0..3
    const int esw  = (frow >> 1) & 7;
    const unsigned xs0 = (unsigned)((kq ^ esw) << 4); // kk=0 slot byte
    const unsigned xs1 = xs0 ^ 64u;                   // kk=1
    const unsigned wmBase = (unsigned)wm * 16384u;    // A-half = wm
    const unsigned bnBase = (unsigned)(wn >> 1) * 16384u;
    const unsigned bnRow  = (unsigned)(wn & 1) * 64u;

    // staging: 1024 chunks/half-tile; thread stages ch0=tid, ch1=512+tid.
    // linear LDS dest; global source pre-swizzled (both-sides rule).
    const int ch0 = tid,           ch1 = 512 + tid;
    const int sr0 = ch0 >> 3,      sr1 = ch1 >> 3;
    const int sc0 = ((ch0 & 7) ^ ((sr0 >> 1) & 7)) << 3;
    const int sc1 = ((ch1 & 7) ^ ((sr1 >> 1) & 7)) << 3;
    const size_t ga0 = (size_t)sr0 * KDIM + sc0;
    const size_t ga1 = (size_t)sr1 * KDIM + sc1;

    f32x4 acc[8][4] = {};
    bf16x8 arE[4], arO[4], brE[4], brO[4];

#define RD16(B) (*(const bf16x8*)(smem + (B)))
#define LDA4(SET, BUFB, MH, XS) do { \
    const unsigned _b = (BUFB) + wmBase; \
    SET[0] = RD16(_b + (unsigned)((MH)*64 +  0 + frow)*128u + (XS)); \
    SET[1] = RD16(_b + (unsigned)((MH)*64 + 16 + frow)*128u + (XS)); \
    SET[2] = RD16(_b + (unsigned)((MH)*64 + 32 + frow)*128u + (XS)); \
    SET[3] = RD16(_b + (unsigned)((MH)*64 + 48 + frow)*128u + (XS)); } while (0)
#define LDB4(SET, BUFB, XS) do { \
    const unsigned _b = (BUFB) + 32768u + bnBase; \
    SET[0] = RD16(_b + (bnRow +  0 + frow)*128u + (XS)); \
    SET[1] = RD16(_b + (bnRow + 16 + frow)*128u + (XS)); \
    SET[2] = RD16(_b + (bnRow + 32 + frow)*128u + (XS)); \
    SET[3] = RD16(_b + (bnRow + 48 + frow)*128u + (XS)); } while (0)
#define STG_A(TSRC, BUFB, H) do { \
    const unsigned _rg = (BUFB) + (H)*16384u; \
    const __hip_bfloat16* _s = Ab + (size_t)(H)*128*KDIM + (size_t)(TSRC)*64; \
    async_load16(_s + ga0, smem + _rg + (unsigned)ch0*16u); \
    async_load16(_s + ga1, smem + _rg + (unsigned)ch1*16u); } while (0)
#define STG_B(TSRC, BUFB, H) do { \
    const unsigned _rg = (BUFB) + 32768u + (H)*16384u; \
    const __hip_bfloat16* _s = Bb + (size_t)(H)*128*KDIM + (size_t)(TSRC)*64; \
    async_load16(_s + ga0, smem + _rg + (unsigned)ch0*16u); \
    async_load16(_s + ga1, smem + _rg + (unsigned)ch1*16u); } while (0)
#define MF16(ASET, BSET, MB) do { \
    __builtin_amdgcn_s_setprio(1); \
    _Pragma("unroll") for (int _m = 0; _m < 4; ++_m) \
    _Pragma("unroll") for (int _n = 0; _n < 4; ++_n) \
        acc[(MB)+_m][_n] = __builtin_amdgcn_mfma_f32_16x16x32_bf16( \
            ASET[_m], BSET[_n], acc[(MB)+_m][_n], 0, 0, 0); \
    __builtin_amdgcn_s_setprio(0); } while (0)
#define DRAIN_LGKM asm volatile("s_waitcnt lgkmcnt(0)" ::: "memory")
#define WAIT_VM4   asm volatile("s_waitcnt vmcnt(4)" ::: "memory")
#define PH_BAR __builtin_amdgcn_s_barrier()

    // ---- prologue: stage K0 (4 halves) + B1 (2) + A1h0; wait K0; read quad0 ----
    STG_B(0, 0u, 0); STG_B(0, 0u, 1);
    STG_A(0, 0u, 0); STG_A(0, 0u, 1);
    STG_B(1, 65536u, 0); STG_B(1, 65536u, 1);
    STG_A(1, 65536u, 0);
    asm volatile("s_waitcnt vmcnt(6)" ::: "memory");
    PH_BAR;
    LDA4(arE, 0u, 0, xs0); LDB4(brE, 0u, xs0);   // quad 0: (t0, mh0, kk0)

#pragma unroll 1
    for (int i = 0; i < NITER; ++i) {
        const int tb = 2 * i + 1;
        const int tc = (2 * i + 2 < 32) ? 2 * i + 2 : 31;  // src clamp; dest buf0
        const int td = (2 * i + 3 < 32) ? 2 * i + 3 : 31;  // src clamp; dest buf1

        // ph1: load q=(ta,mh0,kk1); MFMA q=(ta,mh0,kk0)
        LDA4(arO, 0u, 0, xs1); LDB4(brO, 0u, xs1);
        STG_A(tb, 65536u, 1);
        MF16(arE, brE, 0);
        DRAIN_LGKM; PH_BAR;
        // ph2: load q=(ta,mh1,kk0); MFMA q=(ta,mh0,kk1)
        LDA4(arE, 0u, 1, xs0);
        STG_B(tc, 0u, 0);
        MF16(arO, brO, 0);
        PH_BAR;
        // ph3: load q=(ta,mh1,kk1); MFMA q=(ta,mh1,kk0)
        LDA4(arO, 0u, 1, xs1);
        STG_B(tc, 0u, 1);
        MF16(arE, brE, 4);
        DRAIN_LGKM; WAIT_VM4; PH_BAR;          // tb fully landed for ph4 reads
        // ph4: load q=(tb,mh0,kk0); MFMA q=(ta,mh1,kk1)
        LDA4(arE, 65536u, 0, xs0); LDB4(brE, 65536u, xs0);
        STG_A(tc, 0u, 0);
        MF16(arO, brO, 4);
        PH_BAR;
        // ph5: load q=(tb,mh0,kk1); MFMA q=(tb,mh0,kk0)
        LDA4(arO, 65536u, 0, xs1); LDB4(brO, 65536u, xs1);
        STG_A(tc, 0u, 1);
        MF16(arE, brE, 0);
        DRAIN_LGKM; PH_BAR;
        // ph6: load q=(tb,mh1,kk0); MFMA q=(tb,mh0,kk1)
        LDA4(arE, 65536u, 1, xs0);
        STG_B(td, 65536u, 0);
        MF16(arO, brO, 0);
        PH_BAR;
        // ph7: load q=(tb,mh1,kk1); MFMA q=(tb,mh1,kk0)
        LDA4(arO, 65536u, 1, xs1);
        STG_B(td, 65536u, 1);
        MF16(arE, brE, 4);
        DRAIN_LGKM; WAIT_VM4; PH_BAR;          // tc fully landed for ph8 reads
        // ph8: load q=(tc,mh0,kk0) [dummy at i=15]; MFMA q=(tb,mh1,kk1)
        LDA4(arE, 0u, 0, xs0); LDB4(brE, 0u, xs0);
        STG_A(td, 65536u, 0);
        MF16(arO, brO, 4);
        PH_BAR;
    }
#undef RD16
#undef LDA4
#undef LDB4
#undef STG_A
#undef STG_B
#undef MF16
#undef DRAIN_LGKM
#undef WAIT_VM4
#undef PH_BAR

    // ---- fused epilogue: gates lane-local thanks to B permutation ----
    const int j = bn * 64 + wn * 16 + (lane & 15);
    const float bf_ = Ub[j];
    const float bi_ = Ub[1024 + j];
    const float bo_ = Ub[2048 + j];
    const float bg_ = Ub[3072 + j];
    const int row0 = bm * BM + wm * 128 + ((lane >> 4) << 2);

    float cp[8][4];
#pragma unroll
    for (int m = 0; m < 8; ++m)
#pragma unroll
        for (int r = 0; r < 4; ++r)
            cp[m][r] = c_prev[(size_t)(row0 + m * 16 + r) * HID + j];

#pragma unroll
    for (int m = 0; m < 8; ++m) {
#pragma unroll
        for (int r = 0; r < 4; ++r) {
            const int row = row0 + m * 16 + r;
            const float f  = sigmoidf_(acc[m][0][r] + bf_);
            const float it = sigmoidf_(acc[m][1][r] + bi_);
            const float o  = sigmoidf_(acc[m][2][r] + bo_);
            const float gg = tanhf_(acc[m][3][r] + bg_);
            const float cv = f * cp[m][r] + it * gg;
            const float hv = o * tanhf_(cv);
            out[(size_t)row * HID + j] = hv;
            out[(size_t)BATCH * HID + (size_t)row * HID + j] = cv;
        }
    }
}

// ---------------------------------------------------------------------------
extern "C" void kernel_launch(void* const* d_in, const int* in_sizes, int n_in,
                              void* d_out, int out_size, void* d_ws, size_t ws_size,
                              hipStream_t stream) {
    const float* x      = (const float*)d_in[0];
    const float* h_prev = (const float*)d_in[1];
    const float* c_prev = (const float*)d_in[2];
    const float* U_w    = (const float*)d_in[3];
    const float* U_b    = (const float*)d_in[4];
    const float* W_w    = (const float*)d_in[5];
    float* out = (float*)d_out;

    char* ws = (char*)d_ws;
    __hip_bfloat16* Acat = (__hip_bfloat16*)ws;                      // 16 MB
    __hip_bfloat16* Bcat = (__hip_bfloat16*)(ws + (16u << 20));      // 16 MB

    convert_kernel<<<8192, 256, 0, stream>>>(x, h_prev, U_w, W_w, Acat, Bcat);
    gemm_lstm_kernel<<<256, 512, 0, stream>>>(Acat, Bcat, U_b, c_prev, out);
}